// Round 2
// baseline (343.900 us; speedup 1.0000x reference)
//
#include <hip/hip_runtime.h>

#define NPART 62
#define M     256
#define DD    256
#define NPOS  8
#define NNEG  248
#define MARG  0.2f
#define NBLK  248          // 62 parts x 4 anchor-tiles of 64
#define REC   512

#define OFF_HARD 15376     // 62*248
#define OFF_MD   15438
#define OFF_FN   15439

__global__ __launch_bounds__(512) void triplet_main(
    const float* __restrict__ F, const int* __restrict__ label, float* __restrict__ ws)
{
    // region: two staging buffers [2][256][32] floats (64KB); after GEMM reused as dist[64][256]
    __shared__ __align__(16) float region[16384];
    __shared__ float x2s[M];
    __shared__ float fullS[8][NNEG];
    __shared__ float fullC[8][NNEG];
    __shared__ float posbuf[8][NPOS];
    __shared__ float wred[16];

    const int bxr = blockIdx.x;
    const int swz = (bxr & 7) * 31 + (bxr >> 3);   // bijective: 248 = 8*31, same part -> same XCD
    const int p   = swz >> 2;
    const int ib  = (swz & 3) * 64;                // anchor base within part
    const int t   = threadIdx.x;
    const int tx  = t & 63;                        // lane
    const int ty  = t >> 6;                        // wave 0..7

    const float4* Fv = (const float4*)(F + (size_t)p * (M * DD));  // 64 float4 per row

    // micro-tile: rows ib+ty*8+r (r<8), cols j0+s (s<4)
    const int j0   = tx * 4;
    const int bswz = tx & 7;
    int aoffs[8], asz[8];
#pragma unroll
    for (int r = 0; r < 8; ++r) {
        int ra = ib + ty * 8 + r;
        aoffs[r] = ra * 32;
        asz[r]   = (ra >> 2) & 7;
    }

    // staging assignment: slot = i*512+t -> row = i*64 + (t>>3), k-group q = t&7
    const int srow = t >> 3;
    const int sq   = t & 7;

    float acc[8][4];
#pragma unroll
    for (int r = 0; r < 8; ++r)
#pragma unroll
        for (int s = 0; s < 4; ++s) acc[r][s] = 0.f;
    float x2p[4] = {0.f, 0.f, 0.f, 0.f};

    // prologue: stage kt=0 into buf0 (write-side XOR swizzle on k-group)
#pragma unroll
    for (int i = 0; i < 4; ++i) {
        int row = i * 64 + srow;
        float4 v = Fv[row * 64 + sq];
        int qp = sq ^ ((row >> 2) & 7);
        *(float4*)&region[row * 32 + qp * 4] = v;
    }
    __syncthreads();

    int cur = 0;
    for (int kt = 0; kt < 8; ++kt) {
        float4 st[4];
        if (kt < 7) {   // issue next k-slab loads early; latency hides under compute
#pragma unroll
            for (int i = 0; i < 4; ++i) {
                int row = i * 64 + srow;
                st[i] = Fv[row * 64 + (kt + 1) * 8 + sq];
            }
        }
        const float* B = &region[cur * 8192];
#pragma unroll
        for (int q = 0; q < 8; ++q) {
            float4 a[8], b[4];
#pragma unroll
            for (int r = 0; r < 8; ++r)
                a[r] = *(const float4*)&B[aoffs[r] + ((q ^ asz[r]) << 2)];
#pragma unroll
            for (int s = 0; s < 4; ++s)
                b[s] = *(const float4*)&B[(j0 + s) * 32 + ((q ^ bswz) << 2)];
#pragma unroll
            for (int r = 0; r < 8; ++r)
#pragma unroll
                for (int s = 0; s < 4; ++s)
                    acc[r][s] += a[r].x * b[s].x + a[r].y * b[s].y +
                                 a[r].z * b[s].z + a[r].w * b[s].w;
            if (ty == 0) {  // wave-uniform branch: wave 0 accumulates col x^2
#pragma unroll
                for (int s = 0; s < 4; ++s)
                    x2p[s] += b[s].x * b[s].x + b[s].y * b[s].y +
                              b[s].z * b[s].z + b[s].w * b[s].w;
            }
        }
        if (kt < 7) {
#pragma unroll
            for (int i = 0; i < 4; ++i) {
                int row = i * 64 + srow;
                int qp = sq ^ ((row >> 2) & 7);
                *(float4*)&region[(cur ^ 1) * 8192 + row * 32 + qp * 4] = st[i];
            }
            __syncthreads();
            cur ^= 1;
        }
    }

    if (ty == 0) {
#pragma unroll
        for (int s = 0; s < 4; ++s) x2s[j0 + s] = x2p[s];
    }
    __syncthreads();   // x2s visible; all waves done reading stage buffers

    // dist tile: wave ty writes its own 8 rows (dist[64][256] overlays region)
#pragma unroll
    for (int r = 0; r < 8; ++r) {
        int ia = ty * 8 + r;
        float xi = x2s[ib + ia];
        float dv[4];
#pragma unroll
        for (int s = 0; s < 4; ++s) {
            float d2 = xi + x2s[j0 + s] - 2.f * acc[r][s];
            dv[s] = sqrtf(fmaxf(d2, 0.f) + 1e-12f);
        }
        float4 dr = make_float4(dv[0], dv[1], dv[2], dv[3]);
        *(float4*)&region[ia * 256 + j0] = dr;
    }

    // ---- mining: fully wave-private (wave ty owns anchors ty*8..ty*8+7) ----
    int llab[4];
#pragma unroll
    for (int ch = 0; ch < 4; ++ch) llab[ch] = label[p * M + ch * 64 + tx];

    for (int idx = tx; idx < NNEG; idx += 64) { fullS[ty][idx] = 0.f; fullC[ty][idx] = 0.f; }

    const unsigned long long lmask = (1ull << tx) - 1ull;
    float hardAcc = 0.f, rowSum = 0.f;

    for (int a = 0; a < 8; ++a) {
        const int ii = ty * 8 + a;
        const int gi = ib + ii;
        const int li = label[p * M + gi];   // wave-uniform scalar load
        int runMatch = 0;
        float negmin = 3.4e38f;
        float ndv[4]; int nqv[4]; int nval[4];
#pragma unroll
        for (int ch = 0; ch < 4; ++ch) {
            const int j = ch * 64 + tx;
            float d = region[ii * 256 + j];
            bool match = (llab[ch] == li);
            unsigned long long bal = __ballot(match);
            int posRank = runMatch + __popcll(bal & lmask);
            if (match) {
                if (posRank < NPOS) posbuf[ty][posRank] = d;
                nval[ch] = 0; ndv[ch] = 0.f; nqv[ch] = 0;
            } else {
                ndv[ch] = d; nqv[ch] = j - posRank; nval[ch] = 1;
                negmin = fminf(negmin, d);
            }
            runMatch += __popcll(bal);
            rowSum += d;
        }
        asm volatile("s_waitcnt lgkmcnt(0)" ::: "memory");  // posbuf writes drained (same wave)

        float maxpos = posbuf[ty][0];
#pragma unroll
        for (int pp = 1; pp < NPOS; ++pp) maxpos = fmaxf(maxpos, posbuf[ty][pp]);
#pragma unroll
        for (int off = 32; off >= 1; off >>= 1)
            negmin = fminf(negmin, __shfl_xor(negmin, off));
        hardAcc += fmaxf(MARG + maxpos - negmin, 0.f);

#pragma unroll
        for (int ch = 0; ch < 4; ++ch) {
            if (nval[ch]) {
                float dneg = ndv[ch]; int q = nqv[ch];
                float s = 0.f, cnt = 0.f;
#pragma unroll
                for (int pp = 0; pp < NPOS; ++pp) {
                    float v = MARG + posbuf[ty][pp] - dneg;
                    if (v > 0.f) { s += v; cnt += 1.f; }
                }
                fullS[ty][q] += s;   // per-wave private; q strictly increasing across lanes
                fullC[ty][q] += cnt;
            }
        }
    }

    // block reductions -> ws partial record
#pragma unroll
    for (int off = 32; off >= 1; off >>= 1) rowSum += __shfl_xor(rowSum, off);
    if (tx == 0) { wred[ty] = hardAcc; wred[8 + ty] = rowSum; }
    __syncthreads();

    float* rec = ws + (size_t)swz * REC;
    if (t < NNEG) {
        float s = 0.f, c = 0.f;
#pragma unroll
        for (int w = 0; w < 8; ++w) { s += fullS[w][t]; c += fullC[w][t]; }
        rec[t] = s;
        rec[NNEG + t] = c;
    }
    if (t == 0) {
        float h = 0.f, ds = 0.f;
#pragma unroll
        for (int w = 0; w < 8; ++w) { h += wred[w]; ds += wred[8 + w]; }
        rec[496] = h;
        rec[497] = ds;
    }
}

__global__ __launch_bounds__(256) void triplet_finalize1(const float* __restrict__ ws,
                                                         float* __restrict__ out,
                                                         float* __restrict__ wsP)
{
    const int p = blockIdx.x;
    const int t = threadIdx.x;
    if (t < NNEG) {
        float s = 0.f, c = 0.f;
        for (int a = 0; a < 4; ++a) {
            const float* rec = ws + (size_t)(p * 4 + a) * REC;
            s += rec[t];
            c += rec[NNEG + t];
        }
        out[p * NNEG + t]          = s / (c + 1e-6f);
        out[OFF_FN + p * NNEG + t] = c;
    }
    if (t == 0) {
        float h = 0.f, ds = 0.f;
        for (int a = 0; a < 4; ++a) {
            const float* rec = ws + (size_t)(p * 4 + a) * REC;
            h  += rec[496];
            ds += rec[497];
        }
        out[OFF_HARD + p] = h * (1.0f / 256.0f);
        wsP[p] = ds;
    }
}

__global__ void triplet_finalize2(const float* __restrict__ wsP, float* __restrict__ out)
{
    int t = threadIdx.x;
    float v = (t < NPART) ? wsP[t] : 0.f;
#pragma unroll
    for (int off = 32; off >= 1; off >>= 1) v += __shfl_xor(v, off);
    if (t == 0) out[OFF_MD] = v / (float)((size_t)NPART * M * M);
}

extern "C" void kernel_launch(void* const* d_in, const int* in_sizes, int n_in,
                              void* d_out, int out_size, void* d_ws, size_t ws_size,
                              hipStream_t stream)
{
    const float* F     = (const float*)d_in[0];
    const int*   label = (const int*)d_in[1];
    float*       ws    = (float*)d_ws;
    float*       out   = (float*)d_out;
    float*       wsP   = ws + (size_t)NBLK * REC;

    triplet_main<<<dim3(NBLK), dim3(512), 0, stream>>>(F, label, ws);
    triplet_finalize1<<<dim3(NPART), dim3(256), 0, stream>>>(ws, out, wsP);
    triplet_finalize2<<<dim3(1), dim3(64), 0, stream>>>(wsP, out);
}